// Round 4
// baseline (743.182 us; speedup 1.0000x reference)
//
#include <hip/hip_runtime.h>

// Problem constants (from reference): R=128, T=4096, M=32768, N=4096, L=16384
#define T_DIM 4096
#define R_DIM 128
#define M_DIM 32768
#define N_DIM 4096
#define L_DIM 16384
#define BUCKET_CAP 64   // max rows per node; P(overflow) ~ 1e-18 for Poisson(8)

typedef __attribute__((ext_vector_type(8))) short short8;   // 8 x bf16 (4 VGPRs)
typedef __attribute__((ext_vector_type(4))) float float4_;  // 4 x f32

__device__ __forceinline__ unsigned short f2bf(float f) {
    // round-to-nearest-even fp32 -> bf16 (inputs finite)
    unsigned int u = __float_as_uint(f);
    unsigned int r = (u + 0x7fffu + ((u >> 16) & 1u)) >> 16;
    return (unsigned short)r;
}

// ---------------------------------------------------------------------------
// 1) x_pos = relu(x) -> xpos; Xt[t][k] = bf16(x_pos[k][t]) via LDS transpose
//    so both the global read (along t) and the Xt write (along k) coalesce.
__global__ __launch_bounds__(256) void prep_x(const float* __restrict__ x,
                                              float* __restrict__ xpos,
                                              unsigned short* __restrict__ Xt) {
    __shared__ unsigned short lds[64][130];   // pad 130: write/read both 2-way (free)
    const int tid = threadIdx.x;
    const int t0 = blockIdx.x * 64;
    #pragma unroll
    for (int it = 0; it < 32; it++) {
        int idx = it * 256 + tid;            // [0, 8192)
        int k = idx >> 6;                    // [0, 128)
        int tt = idx & 63;
        float v = fmaxf(x[k * T_DIM + t0 + tt], 0.0f);    // 256B coalesced
        __builtin_nontemporal_store(v, &xpos[k * T_DIM + t0 + tt]);  // output-only
        lds[tt][k] = f2bf(v);
    }
    __syncthreads();
    const int w = tid >> 6, lane = tid & 63;
    #pragma unroll
    for (int rep = 0; rep < 16; rep++) {
        int row = w * 16 + rep;              // t-row within tile
        unsigned int lo = lds[row][2 * lane];
        unsigned int hi = lds[row][2 * lane + 1];
        *(unsigned int*)(Xt + (size_t)(t0 + row) * R_DIM + 2 * lane) = lo | (hi << 16);
    }
}

// ---------------------------------------------------------------------------
// 2) Fused: bucket build (one atomic per movement row) + per-l gcoef/cterm.
//    gcoef[n] = sum_{l: row_node[l]=n} t0*alpha*radio * (1/cap)^beta
//    Identity: (flow*rcap)^beta = flow^beta * rcap^beta (clamp only binds at
//    flow ~ 0 where both forms are < 1e-8 — far under tolerance).
__global__ __launch_bounds__(256) void prep_scatter(const int* __restrict__ node_ids,
                                                    int* __restrict__ cnt,
                                                    int* __restrict__ bucket,
                                                    const float* __restrict__ t0,
                                                    const float* __restrict__ cap,
                                                    const float* __restrict__ radio,
                                                    const float* __restrict__ alpha_raw,
                                                    const float* __restrict__ beta_raw,
                                                    const int* __restrict__ row_node,
                                                    float* __restrict__ gcoef,
                                                    float* __restrict__ cterm) {
    int id = blockIdx.x * 256 + threadIdx.x;   // < 32768
    int n = node_ids[id];
    int slot = atomicAdd(cnt + n, 1);
    if (slot < BUCKET_CAP) bucket[n * BUCKET_CAP + slot] = id;
    if (id < L_DIM) {                          // blocks 0..63 fully active here
        float alpha = 0.01f + 0.99f / (1.0f + expf(-alpha_raw[0]));
        float beta  = 1.0f + 7.0f  / (1.0f + expf(-beta_raw[0]));
        float tv = t0[id], rv = radio[id];
        float rc = 1.0f / cap[id];             // cap in [500,1500] -> rc > 0
        float g = tv * alpha * rv * __builtin_amdgcn_exp2f(beta * __builtin_amdgcn_logf(rc));
        atomicAdd(gcoef + row_node[id], g);
        float p = tv * rv;
        #pragma unroll
        for (int off = 32; off > 0; off >>= 1) p += __shfl_down(p, off, 64);
        if ((threadIdx.x & 63) == 0) atomicAdd(cterm, p);
    }
}

// ---------------------------------------------------------------------------
// 3) Fused: Bb[n][k] = bf16(sum_{m in bucket[n]} A[m][k])  (blocks < 2048)
//          y[t] = cterm                                      (blocks >= 2048)
__global__ __launch_bounds__(256) void bseg_y(const float* __restrict__ A,
                                              const int* __restrict__ cnt,
                                              const int* __restrict__ bucket,
                                              const float* __restrict__ cterm,
                                              unsigned short* __restrict__ Bb,
                                              float* __restrict__ y) {
    if (blockIdx.x >= 2048) {
        int t = (blockIdx.x - 2048) * 256 + threadIdx.x;   // < 4096
        y[t] = cterm[0];
        return;
    }
    int n = blockIdx.x * 2 + (threadIdx.x >> 7);   // < 4096
    int k = threadIdx.x & 127;
    int c = cnt[n];
    c = (c > BUCKET_CAP) ? BUCKET_CAP : c;
    float acc = 0.0f;
    for (int s = 0; s < c; s++) {
        int m = bucket[n * BUCKET_CAP + s];        // wave-uniform -> scalar load
        acc += A[(size_t)m * R_DIM + k];
    }
    Bb[(size_t)n * R_DIM + k] = f2bf(acc);
}

// ---------------------------------------------------------------------------
// 4) Mega-GEMM, one launch, two block-uniform paths:
//    orig <  1024 : y[t] += sum_n gcoef[n] * (Bseg @ x_pos)[n][t]^beta
//                   (nflow never materialized; dispatched FIRST so its
//                    transcendental tail overlaps cpred's write drain)
//    orig >= 1024 : cpred = A @ x_pos, A read f32 + converted in-register
//                   (cast_A kernel and Ab buffer deleted; A panel L2-fits).
//    Both paths: 4 waves (2x2), wave tile 64x64, XCD-chunked swizzle.
//    cpred stores: in-register 4x4 lane transpose -> 16B NT float4 stores
//    (64 -> 16 store instructions per thread, full write-combining).
__global__ __launch_bounds__(256) void megagemm(const float* __restrict__ A,
                                                const unsigned short* __restrict__ Bb,
                                                const unsigned short* __restrict__ Xt,
                                                const float* __restrict__ gcoef,
                                                const float* __restrict__ beta_raw,
                                                float* __restrict__ C,
                                                float* __restrict__ y) {
    const int orig = blockIdx.y * 32 + blockIdx.x;           // grid (32, 288)
    const int lane = threadIdx.x & 63;
    const int wid  = threadIdx.x >> 6;
    const int quad = lane >> 4;
    const int l16  = lane & 15;

    if (orig >= 1024) {
        // ---------------- cpred path ----------------
        const int o2 = orig - 1024;                          // 0..8191
        const int s  = (o2 & 7) * 1024 + (o2 >> 3);          // XCD-chunked, bijective
        const int bx = s & 31, by = s >> 5;                  // bx<32, by<256
        const int mBase = by * 128 + (wid & 1) * 64;
        const int tBase = bx * 128 + (wid >> 1) * 64;

        float4_ acc[4][4];
        #pragma unroll
        for (int i = 0; i < 4; i++)
            #pragma unroll
            for (int j = 0; j < 4; j++)
                acc[i][j] = (float4_)(0.0f);

        #pragma unroll
        for (int ks = 0; ks < 4; ks++) {
            const int k0 = ks * 32 + quad * 8;
            short8 a[4], b[4];
            #pragma unroll
            for (int i = 0; i < 4; i++) {
                const float* ap = A + (size_t)(mBase + i * 16 + l16) * R_DIM + k0;
                float4 f0 = *(const float4*)(ap);
                float4 f1 = *(const float4*)(ap + 4);
                short8 t;
                t[0] = (short)f2bf(f0.x); t[1] = (short)f2bf(f0.y);
                t[2] = (short)f2bf(f0.z); t[3] = (short)f2bf(f0.w);
                t[4] = (short)f2bf(f1.x); t[5] = (short)f2bf(f1.y);
                t[6] = (short)f2bf(f1.z); t[7] = (short)f2bf(f1.w);
                a[i] = t;
            }
            #pragma unroll
            for (int j = 0; j < 4; j++)
                b[j] = *(const short8*)(Xt + (size_t)(tBase + j * 16 + l16) * R_DIM + k0);
            #pragma unroll
            for (int i = 0; i < 4; i++)
                #pragma unroll
                for (int j = 0; j < 4; j++)
                    acc[i][j] = __builtin_amdgcn_mfma_f32_16x16x32_bf16(a[i], b[j], acc[i][j], 0, 0, 0);
        }

        // Epilogue: 4x4 lane transpose within each group-of-4 lanes, then
        // one 16B NT store per (i,j). After transpose: lane g(=lane&3) holds
        // row (quad*4+g), cols G*4..G*4+3 (G = l16>>2). Verified elementwise.
        #pragma unroll
        for (int i = 0; i < 4; i++) {
            #pragma unroll
            for (int j = 0; j < 4; j++) {
                float x0 = acc[i][j][0], x1 = acc[i][j][1];
                float x2 = acc[i][j][2], x3 = acc[i][j][3];
                float t;
                t = __shfl_xor((lane & 1) ? x0 : x1, 1, 64);
                if (lane & 1) x0 = t; else x1 = t;
                t = __shfl_xor((lane & 1) ? x2 : x3, 1, 64);
                if (lane & 1) x2 = t; else x3 = t;
                t = __shfl_xor((lane & 2) ? x0 : x2, 2, 64);
                if (lane & 2) x0 = t; else x2 = t;
                t = __shfl_xor((lane & 2) ? x1 : x3, 2, 64);
                if (lane & 2) x1 = t; else x3 = t;
                float4_ o; o[0] = x0; o[1] = x1; o[2] = x2; o[3] = x3;
                int row  = mBase + i * 16 + quad * 4 + (lane & 3);
                int colb = tBase + j * 16 + (l16 & 12);      // G*4
                __builtin_nontemporal_store(o, (float4_*)(C + (size_t)row * T_DIM + colb));
            }
        }
    } else {
        // ---------------- nflow path ----------------
        const int s  = (orig & 7) * 128 + (orig >> 3);       // 1024 blocks, bijective
        const int bx = s & 31, by = s >> 5;                  // bx<32, by<32
        const int bRow  = by * 128;
        const int mBase = bRow + (wid & 1) * 64;
        const int tBase = bx * 128 + (wid >> 1) * 64;

        __shared__ float gc[128];
        if (threadIdx.x < 128) gc[threadIdx.x] = gcoef[bRow + threadIdx.x];

        float4_ acc[4][4];
        #pragma unroll
        for (int i = 0; i < 4; i++)
            #pragma unroll
            for (int j = 0; j < 4; j++)
                acc[i][j] = (float4_)(0.0f);

        #pragma unroll
        for (int ks = 0; ks < 4; ks++) {
            const int k0 = ks * 32 + quad * 8;
            short8 a[4], b[4];
            #pragma unroll
            for (int i = 0; i < 4; i++)
                a[i] = *(const short8*)(Bb + (size_t)(mBase + i * 16 + l16) * R_DIM + k0);
            #pragma unroll
            for (int j = 0; j < 4; j++)
                b[j] = *(const short8*)(Xt + (size_t)(tBase + j * 16 + l16) * R_DIM + k0);
            #pragma unroll
            for (int i = 0; i < 4; i++)
                #pragma unroll
                for (int j = 0; j < 4; j++)
                    acc[i][j] = __builtin_amdgcn_mfma_f32_16x16x32_bf16(a[i], b[j], acc[i][j], 0, 0, 0);
        }

        __syncthreads();   // gc ready
        float beta = 1.0f + 7.0f / (1.0f + expf(-beta_raw[0]));
        float p[4] = {0.0f, 0.0f, 0.0f, 0.0f};
        #pragma unroll
        for (int i = 0; i < 4; i++) {
            int r0 = (wid & 1) * 64 + i * 16 + quad * 4;     // row - bRow
            #pragma unroll
            for (int r = 0; r < 4; r++) {
                float g = gc[r0 + r];
                #pragma unroll
                for (int j = 0; j < 4; j++) {
                    float f = acc[i][j][r];                  // flow >= 0
                    float pw = __builtin_amdgcn_exp2f(beta * __builtin_amdgcn_logf(fmaxf(f, 1e-30f)));
                    p[j] += g * pw;
                }
            }
        }
        #pragma unroll
        for (int j = 0; j < 4; j++) {
            p[j] += __shfl_xor(p[j], 16, 64);
            p[j] += __shfl_xor(p[j], 32, 64);
            if (quad == 0) atomicAdd(&y[tBase + j * 16 + l16], p[j]);
        }
    }
}

// ---------------------------------------------------------------------------
extern "C" void kernel_launch(void* const* d_in, const int* in_sizes, int n_in,
                              void* d_out, int out_size, void* d_ws, size_t ws_size,
                              hipStream_t stream) {
    const float* x         = (const float*)d_in[0];
    const float* A         = (const float*)d_in[1];
    const float* t0        = (const float*)d_in[2];
    const float* cap       = (const float*)d_in[3];
    const float* radio     = (const float*)d_in[4];
    const float* alpha_raw = (const float*)d_in[5];
    const float* beta_raw  = (const float*)d_in[6];
    const int*   node_ids  = (const int*)d_in[7];
    const int*   row_node  = (const int*)d_in[8];

    float* out   = (float*)d_out;
    float* xpos  = out;                                   // R*T   = 524288
    float* cpred = out + (size_t)R_DIM * T_DIM;           // M*T   = 134217728
    float* y     = cpred + (size_t)M_DIM * T_DIM;         // T     = 4096

    char* ws = (char*)d_ws;
    unsigned short* Xt     = (unsigned short*)(ws);                      // 1 MB
    unsigned short* Bb     = (unsigned short*)(ws + (1u << 20));         // 1 MB
    int*            cnt    = (int*)(ws + (2u << 20));                    // 16 KB
    float*          gcoef  = (float*)(ws + (2u << 20) + N_DIM * 4);      // 16 KB
    float*          csum   = gcoef + N_DIM;                              // 4 B
    int*            bucket = (int*)(ws + (3u << 20));                    // 1 MB

    // zero the atomic-accumulated regions in one memset (cnt|gcoef|csum contiguous)
    (void)hipMemsetAsync(cnt, 0, (size_t)(2 * N_DIM + 1) * 4, stream);

    prep_x      <<<dim3(T_DIM / 64), 256, 0, stream>>>(x, xpos, Xt);
    prep_scatter<<<dim3(M_DIM / 256), 256, 0, stream>>>(node_ids, cnt, bucket,
                                                        t0, cap, radio, alpha_raw,
                                                        beta_raw, row_node, gcoef, csum);
    bseg_y      <<<dim3(2048 + T_DIM / 256), 256, 0, stream>>>(A, cnt, bucket, csum, Bb, y);
    megagemm    <<<dim3(32, 288), 256, 0, stream>>>(A, Bb, Xt, gcoef, beta_raw, cpred, y);
}